// Round 3
// baseline (258.694 us; speedup 1.0000x reference)
//
#include <hip/hip_runtime.h>

#define Bn   2
#define Cn   64
#define Dd   8
#define Hd   128
#define Wd   128
#define HW   16384
#define DHW  131072     // 2^17
#define NPOS 262144     // 2^18
#define NELEM 16777216

typedef __attribute__((ext_vector_type(8))) short short8;
typedef __attribute__((ext_vector_type(4))) float floatx4;

__device__ __forceinline__ short f2bf(float f) {
    union { float f; unsigned u; } v; v.f = f;
    unsigned r = (v.u + 0x7FFFu + ((v.u >> 16) & 1u)) >> 16;   // RNE
    return (short)r;
}
__device__ __forceinline__ float bf2f(short s) {
    union { unsigned u; float f; } v; v.u = ((unsigned)(unsigned short)s) << 16;
    return v.f;
}
// Cheap truncation split: hi = upper16(f), lo = trunc16(f - hi). ~4 VALU ops.
// Pair error ~2^-17 relative — fp32-class for K=64 GEMMs.
__device__ __forceinline__ void split2(float f, short& hi, short& lo) {
    union { float f; unsigned u; } a; a.f = f;
    unsigned hu = a.u & 0xFFFF0000u;
    hi = (short)(hu >> 16);
    union { unsigned u; float f; } hb; hb.u = hu;
    union { float f; unsigned u; } lb; lb.f = f - hb.f;
    lo = (short)(lb.u >> 16);
}

// ---------------------------------------------------------------------------
// k_prep: split-bf16 weights. Wh{h,l}[80][64]: rows 0..63 = head_w,
// rows 64..66 = V^T @ head_w (folds Vp), rows 67..79 = 0. Wt{h,l}[64][64].
// ---------------------------------------------------------------------------
__global__ __launch_bounds__(256) void k_prep(const float* __restrict__ head_w,
                                              const float* __restrict__ tail_w,
                                              const float* __restrict__ V_w,
                                              short* __restrict__ Whh, short* __restrict__ Whl,
                                              short* __restrict__ Wth, short* __restrict__ Wtl)
{
    int t = threadIdx.x;
#pragma unroll
    for (int rep = 0; rep < 16; ++rep) {
        int idx = rep * 256 + t;            // 4096
        short hh, hl;
        split2(head_w[idx], hh, hl);
        Whh[idx] = hh; Whl[idx] = hl;
        split2(tail_w[idx], hh, hl);
        Wth[idx] = hh; Wtl[idx] = hl;
    }
    if (t < 192) {                          // VW[r][i] = sum_c V[c][r]*W[c][i]
        int r = t >> 6, i = t & 63;
        float s = 0.f;
        for (int cc = 0; cc < 64; ++cc) s += V_w[cc * 3 + r] * head_w[cc * 64 + i];
        short hh, hl;
        split2(s, hh, hl);
        Whh[(64 + r) * 64 + i] = hh;
        Whl[(64 + r) * 64 + i] = hl;
    }
#pragma unroll
    for (int rep = 0; rep < 4; ++rep) {     // zero rows 67..79 (832 entries)
        int idx = rep * 256 + t;
        if (idx < 832) { Whh[67 * 64 + idx] = 0; Whl[67 * 64 + idx] = 0; }
    }
}

// ---------------------------------------------------------------------------
// k_headm: [h | Vp] = Wh[80x64] @ x via split-bf16 MFMA (fp32-equivalent).
// Block = 128 positions. Fragment order in LDS; epilogue transposes C through
// LDS (row stride 132 floats, 16B-aligned, bank-optimal b128) so each global
// store instruction covers 2 rows x 512B contiguous.
// ---------------------------------------------------------------------------
__global__ __launch_bounds__(256) void k_headm(const float* __restrict__ x,
                                               const short* __restrict__ Whh,
                                               const short* __restrict__ Whl,
                                               float* __restrict__ h,
                                               float* __restrict__ Vp)
{
    __shared__ __align__(16) char smem[52 * 1024];
    short* Xh = (short*)smem;                    // 16 KB
    short* Xl = (short*)(smem + 16 * 1024);      // 16 KB
    short* Bh = (short*)(smem + 32 * 1024);      // 10 KB
    short* Bl = (short*)(smem + 42 * 1024);      // 10 KB
    float* Cb = (float*)smem;                    // epilogue: 80*132*4 = 42240 B

    int t  = threadIdx.x;
    int p0 = blockIdx.x * 128;
    int b  = p0 >> 17;
    int s0 = p0 & (DHW - 1);
    const float* xb = x + ((size_t)b * Cn) * DHW + s0;

    int pp = t & 127;
    int ho = t >> 7;
#pragma unroll
    for (int pass = 0; pass < 4; ++pass) {
        int in0 = pass * 16 + ho * 8;
        short8 vh, vl;
#pragma unroll
        for (int j = 0; j < 8; ++j) {
            short hh, hl;
            split2(xb[(size_t)(in0 + j) * DHW + pp], hh, hl);
            vh[j] = hh; vl[j] = hl;
        }
        int blk  = ((in0 >> 5) << 3) | (pp >> 4);
        int slot = (((in0 >> 3) & 3) << 4) | (pp & 15);
        *(short8*)&Xh[(blk * 64 + slot) * 8] = vh;
        *(short8*)&Xl[(blk * 64 + slot) * 8] = vl;
    }
#pragma unroll
    for (int pass = 0; pass < 3; ++pass) {   // 640 16B-units of Wh
        int unit = pass * 256 + t;
        if (unit < 640) {
            int o   = unit - (unit / 80) * 80;
            int oc  = unit / 80;
            int in0 = oc * 8;
            int blk  = ((o >> 4) << 1) | (in0 >> 5);
            int slot = (((in0 >> 3) & 3) << 4) | (o & 15);
            *(short8*)&Bh[(blk * 64 + slot) * 8] = *(const short8*)&Whh[o * 64 + in0];
            *(short8*)&Bl[(blk * 64 + slot) * 8] = *(const short8*)&Whl[o * 64 + in0];
        }
    }
    __syncthreads();

    int lane = t & 63;
    int w    = t >> 6;
    floatx4 acc[2][5];
#pragma unroll
    for (int mt = 0; mt < 2; ++mt)
#pragma unroll
        for (int nt = 0; nt < 5; ++nt) acc[mt][nt] = (floatx4)0.f;

    const short8* XhV = (const short8*)Xh;
    const short8* XlV = (const short8*)Xl;
    const short8* BhV = (const short8*)Bh;
    const short8* BlV = (const short8*)Bl;
#pragma unroll
    for (int ks = 0; ks < 2; ++ks) {
        short8 ah0 = XhV[(ks * 8 + w * 2 + 0) * 64 + lane];
        short8 ah1 = XhV[(ks * 8 + w * 2 + 1) * 64 + lane];
        short8 al0 = XlV[(ks * 8 + w * 2 + 0) * 64 + lane];
        short8 al1 = XlV[(ks * 8 + w * 2 + 1) * 64 + lane];
#pragma unroll
        for (int nt = 0; nt < 5; ++nt) {
            short8 bh = BhV[(nt * 2 + ks) * 64 + lane];
            short8 bl = BlV[(nt * 2 + ks) * 64 + lane];
            acc[0][nt] = __builtin_amdgcn_mfma_f32_16x16x32_bf16(al0, bl, acc[0][nt], 0, 0, 0);
            acc[0][nt] = __builtin_amdgcn_mfma_f32_16x16x32_bf16(al0, bh, acc[0][nt], 0, 0, 0);
            acc[0][nt] = __builtin_amdgcn_mfma_f32_16x16x32_bf16(ah0, bl, acc[0][nt], 0, 0, 0);
            acc[0][nt] = __builtin_amdgcn_mfma_f32_16x16x32_bf16(ah0, bh, acc[0][nt], 0, 0, 0);
            acc[1][nt] = __builtin_amdgcn_mfma_f32_16x16x32_bf16(al1, bl, acc[1][nt], 0, 0, 0);
            acc[1][nt] = __builtin_amdgcn_mfma_f32_16x16x32_bf16(al1, bh, acc[1][nt], 0, 0, 0);
            acc[1][nt] = __builtin_amdgcn_mfma_f32_16x16x32_bf16(ah1, bl, acc[1][nt], 0, 0, 0);
            acc[1][nt] = __builtin_amdgcn_mfma_f32_16x16x32_bf16(ah1, bh, acc[1][nt], 0, 0, 0);
        }
    }

    __syncthreads();                        // frag reads done; reuse LDS as Cb
    int outc = lane & 15;
    int quad = lane >> 4;
#pragma unroll
    for (int mt = 0; mt < 2; ++mt)
#pragma unroll
        for (int nt = 0; nt < 5; ++nt) {
            int o   = nt * 16 + outc;
            int pos = w * 32 + mt * 16 + quad * 4;
            *(floatx4*)&Cb[o * 132 + pos] = acc[mt][nt];
        }
    __syncthreads();

    int xr = (t & 31) * 4;                  // 0..124
    int ob = t >> 5;                        // 0..7
#pragma unroll
    for (int pass = 0; pass < 9; ++pass) {
        int o = pass * 8 + ob;
        floatx4 vv = *(const floatx4*)&Cb[o * 132 + xr];
        if (o < 64) {
            *(floatx4*)&h[((size_t)(b * Cn + o)) * DHW + s0 + xr] = vv;
        } else if (o < 67) {
            *(floatx4*)&Vp[((size_t)(b * 3 + (o - 64))) * DHW + s0 + xr] = vv;
        }
    }
}

// ---------------------------------------------------------------------------
// k_uv compute half: d in [D0, D0+4). Needs slices [D0-1, D0+4] clamped ->
// 5 slices. 48 live accumulators (was 96 for the fused version -> VGPR blowup).
// Edges come from __shfl (conflict-free) instead of strided scalar ds_reads
// (which were 8-way bank-conflicted at 16B lane stride).
// ---------------------------------------------------------------------------
template<int D0>
__device__ __forceinline__ void uv_half(const float (*tile)[10][Wd], int yr, int xq, int xl,
                                        const float* __restrict__ U_w,
                                        const float* __restrict__ vpb,
                                        float* __restrict__ uvb)
{
    constexpr int SL0 = (D0 == 0) ? 0 : 3;
    constexpr int SL1 = (D0 == 0) ? 4 : 7;

    float a0[4][4], a1[4][4], a2[4][4];
#pragma unroll
    for (int d = 0; d < 4; ++d)
#pragma unroll
        for (int j = 0; j < 4; ++j) { a0[d][j] = 0.f; a1[d][j] = 0.f; a2[d][j] = 0.f; }

    // wv[kh][0..5] = row window [x-1, x, x+1, x+2, x+3, x+4] (replicate-clamped)
#define CONTRIB(dd, dk)                                                   \
    {                                                                     \
        _Pragma("unroll")                                                 \
        for (int kh = 0; kh < 3; ++kh) {                                  \
            _Pragma("unroll")                                             \
            for (int kw = 0; kw < 3; ++kw) {                              \
                const int kk = (((dk) * 3 + kh) * 3 + kw) * 3;            \
                const float u0 = U_w[kk + 0];                             \
                const float u1 = U_w[kk + 1];                             \
                const float u2 = U_w[kk + 2];                             \
                _Pragma("unroll")                                         \
                for (int j = 0; j < 4; ++j) {                             \
                    a0[dd][j] += wv[kh][kw + j] * u0;                     \
                    a1[dd][j] += wv[kh][kw + j] * u1;                     \
                    a2[dd][j] += wv[kh][kw + j] * u2;                     \
                }                                                         \
            }                                                             \
        }                                                                 \
    }

#pragma unroll
    for (int sl = SL0; sl <= SL1; ++sl) {
        float wv[3][6];
#pragma unroll
        for (int kh = 0; kh < 3; ++kh) {
            floatx4 c = *(const floatx4*)&tile[sl][yr + kh][xq];
            float lf = __shfl_up(c[3], 1u);     // lane-1's last elem = row[xq-1]
            float rt = __shfl_down(c[0], 1u);   // lane+1's first elem = row[xq+4]
            wv[kh][0] = (xl == 0)  ? c[0] : lf;
            wv[kh][1] = c[0]; wv[kh][2] = c[1]; wv[kh][3] = c[2]; wv[kh][4] = c[3];
            wv[kh][5] = (xl == 31) ? c[3] : rt;
        }
        if (sl >= D0 && sl <= D0 + 3)                   CONTRIB(sl - D0, 1);      // dk=1 -> d=sl
        if (sl + 1 >= D0 && sl + 1 <= D0 + 3)           CONTRIB(sl + 1 - D0, 0);  // dk=0 -> d=sl+1
        if (sl - 1 >= D0 && sl - 1 <= D0 + 3 && sl > 0) CONTRIB(sl - 1 - D0, 2);  // dk=2 -> d=sl-1
        if (D0 == 0 && sl == 0)                         CONTRIB(0, 0);            // clamp low
        if (D0 == 4 && sl == 7)                         CONTRIB(3, 2);            // clamp high
    }
#undef CONTRIB

#pragma unroll
    for (int d = 0; d < 4; ++d) {
        const int dg = D0 + d;
        floatx4 v0 = *(const floatx4*)(vpb + (size_t)dg * HW);
        floatx4 v1 = *(const floatx4*)(vpb + (size_t)DHW + (size_t)dg * HW);
        floatx4 v2 = *(const floatx4*)(vpb + (size_t)2 * DHW + (size_t)dg * HW);
        floatx4 ov;
#pragma unroll
        for (int j = 0; j < 4; ++j) {
            float nrm = sqrtf(a0[d][j] * a0[d][j] + a1[d][j] * a1[d][j] + a2[d][j] * a2[d][j]);
            float inv = 1.f / (1e-6f + nrm);
            ov[j] = (a0[d][j] * v0[j] + a1[d][j] * v1[j] + a2[d][j] * v2[j]) * inv;
        }
        *(floatx4*)(uvb + (size_t)dg * HW) = ov;
    }
}

// ---------------------------------------------------------------------------
// k_uv: fp32 depthwise 3x3x3 (replicate pad) -> l2norm over r -> dot Vp.
// W-vectorized x4, computed in two d-halves to keep live accumulators at 48.
// ---------------------------------------------------------------------------
__global__ __launch_bounds__(256) void k_uv(const float* __restrict__ h,
                                            const float* __restrict__ Vp,
                                            const float* __restrict__ U_w,
                                            float* __restrict__ UV)
{
    __shared__ float tile[Dd][10][Wd];  // 40 KB: rows y0-1 .. y0+8 (clamped)

    int blk = blockIdx.x;
    int yt  = blk & 15;                 // 16 tiles of 8 rows
    int bc  = blk >> 4;                 // b*64 + c
    int b   = bc >> 6;
    int y0  = yt * 8;
    int t   = threadIdx.x;

    const float* hb = h + (size_t)bc * DHW;
#pragma unroll
    for (int rep = 0; rep < 10; ++rep) {   // 2560 float4 units = 8 D x 10 rows x 32
        int idx = rep * 256 + t;
        int d   = idx / 320;
        int rem = idx - d * 320;
        int lr  = rem >> 5;
        int x4  = (rem & 31) * 4;
        int zy  = y0 - 1 + lr;
        zy = zy < 0 ? 0 : (zy > Hd - 1 ? Hd - 1 : zy);
        *(floatx4*)&tile[d][lr][x4] = *(const floatx4*)(hb + d * HW + zy * Wd + x4);
    }
    __syncthreads();

    int xl = t & 31;                    // 32 lanes across W
    int yr = t >> 5;                    // 8 output rows
    int xq = xl * 4;
    int y  = y0 + yr;

    const float* vpb = Vp + (size_t)b * 3 * DHW + y * Wd + xq;
    float* uvb       = UV + (size_t)bc * DHW + y * Wd + xq;

    uv_half<0>(tile, yr, xq, xl, U_w, vpb, uvb);
    uv_half<4>(tile, yr, xq, xl, U_w, vpb, uvb);
}

// ---------------------------------------------------------------------------
// k_tailm: out = Wt[64x64] @ UV via split-bf16 MFMA, LDS-transposed epilogue.
// ---------------------------------------------------------------------------
__global__ __launch_bounds__(256) void k_tailm(const float* __restrict__ UV,
                                               const short* __restrict__ Wth,
                                               const short* __restrict__ Wtl,
                                               float* __restrict__ out)
{
    __shared__ __align__(16) char smem[48 * 1024];
    short* Xh = (short*)smem;                    // 16 KB
    short* Xl = (short*)(smem + 16 * 1024);      // 16 KB
    short* Bh = (short*)(smem + 32 * 1024);      // 8 KB
    short* Bl = (short*)(smem + 40 * 1024);      // 8 KB
    float* Cb = (float*)smem;                    // 64*132*4 = 33792 B

    int t  = threadIdx.x;
    int p0 = blockIdx.x * 128;
    int b  = p0 >> 17;
    int s0 = p0 & (DHW - 1);
    const float* ub = UV + ((size_t)b * Cn) * DHW + s0;

    int pp = t & 127;
    int ho = t >> 7;
#pragma unroll
    for (int pass = 0; pass < 4; ++pass) {
        int in0 = pass * 16 + ho * 8;
        short8 vh, vl;
#pragma unroll
        for (int j = 0; j < 8; ++j) {
            short hh, hl;
            split2(ub[(size_t)(in0 + j) * DHW + pp], hh, hl);
            vh[j] = hh; vl[j] = hl;
        }
        int blk  = ((in0 >> 5) << 3) | (pp >> 4);
        int slot = (((in0 >> 3) & 3) << 4) | (pp & 15);
        *(short8*)&Xh[(blk * 64 + slot) * 8] = vh;
        *(short8*)&Xl[(blk * 64 + slot) * 8] = vl;
    }
#pragma unroll
    for (int pass = 0; pass < 2; ++pass) {   // 512 16B-units of Wt
        int unit = pass * 256 + t;
        int o    = unit & 63;
        int oc   = unit >> 6;
        int in0  = oc * 8;
        int blk  = ((o >> 4) << 1) | (in0 >> 5);
        int slot = (((in0 >> 3) & 3) << 4) | (o & 15);
        *(short8*)&Bh[(blk * 64 + slot) * 8] = *(const short8*)&Wth[o * 64 + in0];
        *(short8*)&Bl[(blk * 64 + slot) * 8] = *(const short8*)&Wtl[o * 64 + in0];
    }
    __syncthreads();

    int lane = t & 63;
    int w    = t >> 6;
    floatx4 acc[2][4];
#pragma unroll
    for (int mt = 0; mt < 2; ++mt)
#pragma unroll
        for (int nt = 0; nt < 4; ++nt) acc[mt][nt] = (floatx4)0.f;

    const short8* XhV = (const short8*)Xh;
    const short8* XlV = (const short8*)Xl;
    const short8* BhV = (const short8*)Bh;
    const short8* BlV = (const short8*)Bl;
#pragma unroll
    for (int ks = 0; ks < 2; ++ks) {
        short8 ah0 = XhV[(ks * 8 + w * 2 + 0) * 64 + lane];
        short8 ah1 = XhV[(ks * 8 + w * 2 + 1) * 64 + lane];
        short8 al0 = XlV[(ks * 8 + w * 2 + 0) * 64 + lane];
        short8 al1 = XlV[(ks * 8 + w * 2 + 1) * 64 + lane];
#pragma unroll
        for (int nt = 0; nt < 4; ++nt) {
            short8 bh = BhV[(nt * 2 + ks) * 64 + lane];
            short8 bl = BlV[(nt * 2 + ks) * 64 + lane];
            acc[0][nt] = __builtin_amdgcn_mfma_f32_16x16x32_bf16(al0, bl, acc[0][nt], 0, 0, 0);
            acc[0][nt] = __builtin_amdgcn_mfma_f32_16x16x32_bf16(al0, bh, acc[0][nt], 0, 0, 0);
            acc[0][nt] = __builtin_amdgcn_mfma_f32_16x16x32_bf16(ah0, bl, acc[0][nt], 0, 0, 0);
            acc[0][nt] = __builtin_amdgcn_mfma_f32_16x16x32_bf16(ah0, bh, acc[0][nt], 0, 0, 0);
            acc[1][nt] = __builtin_amdgcn_mfma_f32_16x16x32_bf16(al1, bl, acc[1][nt], 0, 0, 0);
            acc[1][nt] = __builtin_amdgcn_mfma_f32_16x16x32_bf16(al1, bh, acc[1][nt], 0, 0, 0);
            acc[1][nt] = __builtin_amdgcn_mfma_f32_16x16x32_bf16(ah1, bl, acc[1][nt], 0, 0, 0);
            acc[1][nt] = __builtin_amdgcn_mfma_f32_16x16x32_bf16(ah1, bh, acc[1][nt], 0, 0, 0);
        }
    }

    __syncthreads();
    int outc = lane & 15;
    int quad = lane >> 4;
#pragma unroll
    for (int mt = 0; mt < 2; ++mt)
#pragma unroll
        for (int nt = 0; nt < 4; ++nt) {
            int o   = nt * 16 + outc;
            int pos = w * 32 + mt * 16 + quad * 4;
            *(floatx4*)&Cb[o * 132 + pos] = acc[mt][nt];
        }
    __syncthreads();

    int xr = (t & 31) * 4;
    int ob = t >> 5;
#pragma unroll
    for (int pass = 0; pass < 8; ++pass) {
        int o = pass * 8 + ob;
        floatx4 vv = *(const floatx4*)&Cb[o * 132 + xr];
        *(floatx4*)&out[((size_t)(b * Cn + o)) * DHW + s0 + xr] = vv;
    }
}

extern "C" void kernel_launch(void* const* d_in, const int* in_sizes, int n_in,
                              void* d_out, int out_size, void* d_ws, size_t ws_size,
                              hipStream_t stream)
{
    const float* x      = (const float*)d_in[0];
    const float* head_w = (const float*)d_in[1];
    const float* tail_w = (const float*)d_in[2];
    const float* U_w    = (const float*)d_in[3];
    const float* V_w    = (const float*)d_in[4];
    float* out = (float*)d_out;

    // ws: h fp32 (64MB) | Vp fp32 (3MB) | UV fp32 (64MB) | split weights
    float* h   = (float*)d_ws;
    float* Vp  = h + (size_t)NELEM;
    float* UVf = Vp + (size_t)Bn * 3 * DHW;
    short* Whh = (short*)(UVf + (size_t)NELEM);
    short* Whl = Whh + 80 * 64;
    short* Wth = Whl + 80 * 64;
    short* Wtl = Wth + 64 * 64;

    k_prep<<<1, 256, 0, stream>>>(head_w, tail_w, V_w, Whh, Whl, Wth, Wtl);
    k_headm<<<NPOS / 128, 256, 0, stream>>>(x, Whh, Whl, h, Vp);
    k_uv<<<Bn * Cn * (Hd / 8), 256, 0, stream>>>(h, Vp, U_w, UVf);
    k_tailm<<<NPOS / 128, 256, 0, stream>>>(UVf, Wth, Wtl, out);
}

// Round 4
// 234.398 us; speedup vs baseline: 1.1037x; 1.1037x over previous
//
#include <hip/hip_runtime.h>

#define Bn   2
#define Cn   64
#define Dd   8
#define Hd   128
#define Wd   128
#define HW   16384
#define DHW  131072     // 2^17
#define NPOS 262144     // 2^18
#define NELEM 16777216

typedef __attribute__((ext_vector_type(8))) short short8;
typedef __attribute__((ext_vector_type(4))) float floatx4;

__device__ __forceinline__ short f2bf(float f) {
    union { float f; unsigned u; } v; v.f = f;
    unsigned r = (v.u + 0x7FFFu + ((v.u >> 16) & 1u)) >> 16;   // RNE
    return (short)r;
}
__device__ __forceinline__ float bf2f(short s) {
    union { unsigned u; float f; } v; v.u = ((unsigned)(unsigned short)s) << 16;
    return v.f;
}
// Cheap truncation split: hi = upper16(f), lo = trunc16(f - hi). ~4 VALU ops.
// Pair error ~2^-17 relative — fp32-class for K=64 GEMMs.
__device__ __forceinline__ void split2(float f, short& hi, short& lo) {
    union { float f; unsigned u; } a; a.f = f;
    unsigned hu = a.u & 0xFFFF0000u;
    hi = (short)(hu >> 16);
    union { unsigned u; float f; } hb; hb.u = hu;
    union { float f; unsigned u; } lb; lb.f = f - hb.f;
    lo = (short)(lb.u >> 16);
}

// ---------------------------------------------------------------------------
// k_prep: split-bf16 weights. Wh{h,l}[80][64]: rows 0..63 = head_w,
// rows 64..66 = V^T @ head_w (folds Vp), rows 67..79 = 0. Wt{h,l}[64][64].
// ---------------------------------------------------------------------------
__global__ __launch_bounds__(256) void k_prep(const float* __restrict__ head_w,
                                              const float* __restrict__ tail_w,
                                              const float* __restrict__ V_w,
                                              short* __restrict__ Whh, short* __restrict__ Whl,
                                              short* __restrict__ Wth, short* __restrict__ Wtl)
{
    int t = threadIdx.x;
#pragma unroll
    for (int rep = 0; rep < 16; ++rep) {
        int idx = rep * 256 + t;            // 4096
        short hh, hl;
        split2(head_w[idx], hh, hl);
        Whh[idx] = hh; Whl[idx] = hl;
        split2(tail_w[idx], hh, hl);
        Wth[idx] = hh; Wtl[idx] = hl;
    }
    if (t < 192) {                          // VW[r][i] = sum_c V[c][r]*W[c][i]
        int r = t >> 6, i = t & 63;
        float s = 0.f;
        for (int cc = 0; cc < 64; ++cc) s += V_w[cc * 3 + r] * head_w[cc * 64 + i];
        short hh, hl;
        split2(s, hh, hl);
        Whh[(64 + r) * 64 + i] = hh;
        Whl[(64 + r) * 64 + i] = hl;
    }
#pragma unroll
    for (int rep = 0; rep < 4; ++rep) {     // zero rows 67..79 (832 entries)
        int idx = rep * 256 + t;
        if (idx < 832) { Whh[67 * 64 + idx] = 0; Whl[67 * 64 + idx] = 0; }
    }
}

// ---------------------------------------------------------------------------
// k_headm: [h | Vp] = Wh[80x64] @ x via split-bf16 MFMA (fp32-equivalent).
// 3-product split: ah*bh + ah*bl + al*bh (al*bl term ~2^-16 rel, dropped).
// Block = 128 positions. Fragment order in LDS; epilogue transposes C through
// LDS (row stride 132 floats, 16B-aligned, bank-optimal b128) so each global
// store instruction covers 2 rows x 512B contiguous.
// ---------------------------------------------------------------------------
__global__ __launch_bounds__(256) void k_headm(const float* __restrict__ x,
                                               const short* __restrict__ Whh,
                                               const short* __restrict__ Whl,
                                               float* __restrict__ h,
                                               float* __restrict__ Vp)
{
    __shared__ __align__(16) char smem[52 * 1024];
    short* Xh = (short*)smem;                    // 16 KB
    short* Xl = (short*)(smem + 16 * 1024);      // 16 KB
    short* Bh = (short*)(smem + 32 * 1024);      // 10 KB
    short* Bl = (short*)(smem + 42 * 1024);      // 10 KB
    float* Cb = (float*)smem;                    // epilogue: 80*132*4 = 42240 B

    int t  = threadIdx.x;
    int p0 = blockIdx.x * 128;
    int b  = p0 >> 17;
    int s0 = p0 & (DHW - 1);
    const float* xb = x + ((size_t)b * Cn) * DHW + s0;

    int pp = t & 127;
    int ho = t >> 7;
#pragma unroll
    for (int pass = 0; pass < 4; ++pass) {
        int in0 = pass * 16 + ho * 8;
        short8 vh, vl;
#pragma unroll
        for (int j = 0; j < 8; ++j) {
            short hh, hl;
            split2(xb[(size_t)(in0 + j) * DHW + pp], hh, hl);
            vh[j] = hh; vl[j] = hl;
        }
        int blk  = ((in0 >> 5) << 3) | (pp >> 4);
        int slot = (((in0 >> 3) & 3) << 4) | (pp & 15);
        *(short8*)&Xh[(blk * 64 + slot) * 8] = vh;
        *(short8*)&Xl[(blk * 64 + slot) * 8] = vl;
    }
#pragma unroll
    for (int pass = 0; pass < 3; ++pass) {   // 640 16B-units of Wh
        int unit = pass * 256 + t;
        if (unit < 640) {
            int o   = unit - (unit / 80) * 80;
            int oc  = unit / 80;
            int in0 = oc * 8;
            int blk  = ((o >> 4) << 1) | (in0 >> 5);
            int slot = (((in0 >> 3) & 3) << 4) | (o & 15);
            *(short8*)&Bh[(blk * 64 + slot) * 8] = *(const short8*)&Whh[o * 64 + in0];
            *(short8*)&Bl[(blk * 64 + slot) * 8] = *(const short8*)&Whl[o * 64 + in0];
        }
    }
    __syncthreads();

    int lane = t & 63;
    int w    = t >> 6;
    floatx4 acc[2][5];
#pragma unroll
    for (int mt = 0; mt < 2; ++mt)
#pragma unroll
        for (int nt = 0; nt < 5; ++nt) acc[mt][nt] = (floatx4)0.f;

    const short8* XhV = (const short8*)Xh;
    const short8* XlV = (const short8*)Xl;
    const short8* BhV = (const short8*)Bh;
    const short8* BlV = (const short8*)Bl;
#pragma unroll
    for (int ks = 0; ks < 2; ++ks) {
        short8 ah0 = XhV[(ks * 8 + w * 2 + 0) * 64 + lane];
        short8 ah1 = XhV[(ks * 8 + w * 2 + 1) * 64 + lane];
        short8 al0 = XlV[(ks * 8 + w * 2 + 0) * 64 + lane];
        short8 al1 = XlV[(ks * 8 + w * 2 + 1) * 64 + lane];
#pragma unroll
        for (int nt = 0; nt < 5; ++nt) {
            short8 bh = BhV[(nt * 2 + ks) * 64 + lane];
            short8 bl = BlV[(nt * 2 + ks) * 64 + lane];
            acc[0][nt] = __builtin_amdgcn_mfma_f32_16x16x32_bf16(al0, bh, acc[0][nt], 0, 0, 0);
            acc[0][nt] = __builtin_amdgcn_mfma_f32_16x16x32_bf16(ah0, bl, acc[0][nt], 0, 0, 0);
            acc[0][nt] = __builtin_amdgcn_mfma_f32_16x16x32_bf16(ah0, bh, acc[0][nt], 0, 0, 0);
            acc[1][nt] = __builtin_amdgcn_mfma_f32_16x16x32_bf16(al1, bh, acc[1][nt], 0, 0, 0);
            acc[1][nt] = __builtin_amdgcn_mfma_f32_16x16x32_bf16(ah1, bl, acc[1][nt], 0, 0, 0);
            acc[1][nt] = __builtin_amdgcn_mfma_f32_16x16x32_bf16(ah1, bh, acc[1][nt], 0, 0, 0);
        }
    }

    __syncthreads();                        // frag reads done; reuse LDS as Cb
    int outc = lane & 15;
    int quad = lane >> 4;
#pragma unroll
    for (int mt = 0; mt < 2; ++mt)
#pragma unroll
        for (int nt = 0; nt < 5; ++nt) {
            int o   = nt * 16 + outc;
            int pos = w * 32 + mt * 16 + quad * 4;
            *(floatx4*)&Cb[o * 132 + pos] = acc[mt][nt];
        }
    __syncthreads();

    int xr = (t & 31) * 4;                  // 0..124
    int ob = t >> 5;                        // 0..7
#pragma unroll
    for (int pass = 0; pass < 9; ++pass) {
        int o = pass * 8 + ob;
        floatx4 vv = *(const floatx4*)&Cb[o * 132 + xr];
        if (o < 64) {
            *(floatx4*)&h[((size_t)(b * Cn + o)) * DHW + s0 + xr] = vv;
        } else if (o < 67) {
            *(floatx4*)&Vp[((size_t)(b * 3 + (o - 64))) * DHW + s0 + xr] = vv;
        }
    }
}

// ---------------------------------------------------------------------------
// k_uv: fp32 depthwise 3x3x3 (replicate pad) -> l2norm over r -> dot Vp.
// Slice-major register schedule: each of 8 LDS slices is read ONCE (9 values)
// and contributed to the <=3 outputs it feeds (72 ds_reads vs 216).
// 2-row tile / 16 KB LDS: best measured wall config (h is L3-resident
// in-graph, so the 2x h re-read is cheap; occupancy is what matters).
// ---------------------------------------------------------------------------
__global__ __launch_bounds__(256) void k_uv(const float* __restrict__ h,
                                            const float* __restrict__ Vp,
                                            const float* __restrict__ U_w,
                                            float* __restrict__ UV)
{
    __shared__ float tile[Dd][4][Wd];   // 16 KB

    int blk = blockIdx.x;
    int yt  = blk & 63;
    int bc  = blk >> 6;                 // b*64 + c
    int b   = bc >> 6;
    int y0  = yt * 2;
    int t   = threadIdx.x;

    const float* hb = h + (size_t)bc * DHW;
#pragma unroll
    for (int rep = 0; rep < 4; ++rep) {   // 1024 float4 units
        int idx = rep * 256 + t;
        int d   = idx >> 7;
        int rem = idx & 127;
        int yr  = rem >> 5;
        int x4  = (rem & 31) * 4;
        int zy  = y0 - 1 + yr;
        zy = zy < 0 ? 0 : (zy > Hd - 1 ? Hd - 1 : zy);
        *(floatx4*)&tile[d][yr][x4] = *(const floatx4*)(hb + d * HW + zy * Wd + x4);
    }
    __syncthreads();

    int xx = t & 127;
    int yr = t >> 7;
    int y  = y0 + yr;
    int xm = xx - 1; if (xm < 0) xm = 0;
    int xp = xx + 1; if (xp > Wd - 1) xp = Wd - 1;

    float a0[8], a1[8], a2[8];
#pragma unroll
    for (int d = 0; d < 8; ++d) { a0[d] = 0.f; a1[d] = 0.f; a2[d] = 0.f; }

#define CONTRIB(dd, dk)                                                   \
    {                                                                     \
        _Pragma("unroll")                                                 \
        for (int kh = 0; kh < 3; ++kh) {                                  \
            _Pragma("unroll")                                             \
            for (int kw = 0; kw < 3; ++kw) {                              \
                const int kk = (((dk) * 3 + kh) * 3 + kw) * 3;            \
                a0[dd] += v[kh][kw] * U_w[kk + 0];                        \
                a1[dd] += v[kh][kw] * U_w[kk + 1];                        \
                a2[dd] += v[kh][kw] * U_w[kk + 2];                        \
            }                                                             \
        }                                                                 \
    }

#pragma unroll
    for (int sl = 0; sl < 8; ++sl) {
        float v[3][3];
#pragma unroll
        for (int kh = 0; kh < 3; ++kh) {
            const float* row = &tile[sl][yr + kh][0];
            v[kh][0] = row[xm]; v[kh][1] = row[xx]; v[kh][2] = row[xp];
        }
        CONTRIB(sl, 1);                         // dk=1 -> d = sl
        if (sl == 0) CONTRIB(0, 0);             // replicate clamp low
        if (sl < 7)  CONTRIB(sl + 1, 0);        // dk=0 -> d = sl+1
        if (sl > 0)  CONTRIB(sl - 1, 2);        // dk=2 -> d = sl-1
        if (sl == 7) CONTRIB(7, 2);             // replicate clamp high
    }
#undef CONTRIB

    const float* vpb = Vp + (size_t)b * 3 * DHW + y * Wd + xx;
    float* uvb       = UV + (size_t)bc * DHW + y * Wd + xx;
#pragma unroll
    for (int d = 0; d < 8; ++d) {
        float nrm = sqrtf(a0[d] * a0[d] + a1[d] * a1[d] + a2[d] * a2[d]);
        float inv = 1.f / (1e-6f + nrm);
        float uv = (a0[d] * vpb[(size_t)d * HW]
                  + a1[d] * vpb[(size_t)DHW + d * HW]
                  + a2[d] * vpb[(size_t)2 * DHW + d * HW]) * inv;
        uvb[(size_t)d * HW] = uv;
    }
}

// ---------------------------------------------------------------------------
// k_tailm: out = Wt[64x64] @ UV via split-bf16 MFMA (3-product split),
// LDS-transposed epilogue.
// ---------------------------------------------------------------------------
__global__ __launch_bounds__(256) void k_tailm(const float* __restrict__ UV,
                                               const short* __restrict__ Wth,
                                               const short* __restrict__ Wtl,
                                               float* __restrict__ out)
{
    __shared__ __align__(16) char smem[48 * 1024];
    short* Xh = (short*)smem;                    // 16 KB
    short* Xl = (short*)(smem + 16 * 1024);      // 16 KB
    short* Bh = (short*)(smem + 32 * 1024);      // 8 KB
    short* Bl = (short*)(smem + 40 * 1024);      // 8 KB
    float* Cb = (float*)smem;                    // 64*132*4 = 33792 B

    int t  = threadIdx.x;
    int p0 = blockIdx.x * 128;
    int b  = p0 >> 17;
    int s0 = p0 & (DHW - 1);
    const float* ub = UV + ((size_t)b * Cn) * DHW + s0;

    int pp = t & 127;
    int ho = t >> 7;
#pragma unroll
    for (int pass = 0; pass < 4; ++pass) {
        int in0 = pass * 16 + ho * 8;
        short8 vh, vl;
#pragma unroll
        for (int j = 0; j < 8; ++j) {
            short hh, hl;
            split2(ub[(size_t)(in0 + j) * DHW + pp], hh, hl);
            vh[j] = hh; vl[j] = hl;
        }
        int blk  = ((in0 >> 5) << 3) | (pp >> 4);
        int slot = (((in0 >> 3) & 3) << 4) | (pp & 15);
        *(short8*)&Xh[(blk * 64 + slot) * 8] = vh;
        *(short8*)&Xl[(blk * 64 + slot) * 8] = vl;
    }
#pragma unroll
    for (int pass = 0; pass < 2; ++pass) {   // 512 16B-units of Wt
        int unit = pass * 256 + t;
        int o    = unit & 63;
        int oc   = unit >> 6;
        int in0  = oc * 8;
        int blk  = ((o >> 4) << 1) | (in0 >> 5);
        int slot = (((in0 >> 3) & 3) << 4) | (o & 15);
        *(short8*)&Bh[(blk * 64 + slot) * 8] = *(const short8*)&Wth[o * 64 + in0];
        *(short8*)&Bl[(blk * 64 + slot) * 8] = *(const short8*)&Wtl[o * 64 + in0];
    }
    __syncthreads();

    int lane = t & 63;
    int w    = t >> 6;
    floatx4 acc[2][4];
#pragma unroll
    for (int mt = 0; mt < 2; ++mt)
#pragma unroll
        for (int nt = 0; nt < 4; ++nt) acc[mt][nt] = (floatx4)0.f;

    const short8* XhV = (const short8*)Xh;
    const short8* XlV = (const short8*)Xl;
    const short8* BhV = (const short8*)Bh;
    const short8* BlV = (const short8*)Bl;
#pragma unroll
    for (int ks = 0; ks < 2; ++ks) {
        short8 ah0 = XhV[(ks * 8 + w * 2 + 0) * 64 + lane];
        short8 ah1 = XhV[(ks * 8 + w * 2 + 1) * 64 + lane];
        short8 al0 = XlV[(ks * 8 + w * 2 + 0) * 64 + lane];
        short8 al1 = XlV[(ks * 8 + w * 2 + 1) * 64 + lane];
#pragma unroll
        for (int nt = 0; nt < 4; ++nt) {
            short8 bh = BhV[(nt * 2 + ks) * 64 + lane];
            short8 bl = BlV[(nt * 2 + ks) * 64 + lane];
            acc[0][nt] = __builtin_amdgcn_mfma_f32_16x16x32_bf16(al0, bh, acc[0][nt], 0, 0, 0);
            acc[0][nt] = __builtin_amdgcn_mfma_f32_16x16x32_bf16(ah0, bl, acc[0][nt], 0, 0, 0);
            acc[0][nt] = __builtin_amdgcn_mfma_f32_16x16x32_bf16(ah0, bh, acc[0][nt], 0, 0, 0);
            acc[1][nt] = __builtin_amdgcn_mfma_f32_16x16x32_bf16(al1, bh, acc[1][nt], 0, 0, 0);
            acc[1][nt] = __builtin_amdgcn_mfma_f32_16x16x32_bf16(ah1, bl, acc[1][nt], 0, 0, 0);
            acc[1][nt] = __builtin_amdgcn_mfma_f32_16x16x32_bf16(ah1, bh, acc[1][nt], 0, 0, 0);
        }
    }

    __syncthreads();
    int outc = lane & 15;
    int quad = lane >> 4;
#pragma unroll
    for (int mt = 0; mt < 2; ++mt)
#pragma unroll
        for (int nt = 0; nt < 4; ++nt) {
            int o   = nt * 16 + outc;
            int pos = w * 32 + mt * 16 + quad * 4;
            *(floatx4*)&Cb[o * 132 + pos] = acc[mt][nt];
        }
    __syncthreads();

    int xr = (t & 31) * 4;
    int ob = t >> 5;
#pragma unroll
    for (int pass = 0; pass < 8; ++pass) {
        int o = pass * 8 + ob;
        floatx4 vv = *(const floatx4*)&Cb[o * 132 + xr];
        *(floatx4*)&out[((size_t)(b * Cn + o)) * DHW + s0 + xr] = vv;
    }
}

extern "C" void kernel_launch(void* const* d_in, const int* in_sizes, int n_in,
                              void* d_out, int out_size, void* d_ws, size_t ws_size,
                              hipStream_t stream)
{
    const float* x      = (const float*)d_in[0];
    const float* head_w = (const float*)d_in[1];
    const float* tail_w = (const float*)d_in[2];
    const float* U_w    = (const float*)d_in[3];
    const float* V_w    = (const float*)d_in[4];
    float* out = (float*)d_out;

    // ws: h fp32 (64MB) | Vp fp32 (3MB) | UV fp32 (64MB) | split weights
    float* h   = (float*)d_ws;
    float* Vp  = h + (size_t)NELEM;
    float* UVf = Vp + (size_t)Bn * 3 * DHW;
    short* Whh = (short*)(UVf + (size_t)NELEM);
    short* Whl = Whh + 80 * 64;
    short* Wth = Whl + 80 * 64;
    short* Wtl = Wth + 64 * 64;

    k_prep<<<1, 256, 0, stream>>>(head_w, tail_w, V_w, Whh, Whl, Wth, Wtl);
    k_headm<<<NPOS / 128, 256, 0, stream>>>(x, Whh, Whl, h, Vp);
    k_uv<<<Bn * Cn * (Hd / 2), 256, 0, stream>>>(h, Vp, U_w, UVf);
    k_tailm<<<NPOS / 128, 256, 0, stream>>>(UVf, Wth, Wtl, out);
}

// Round 5
// 220.088 us; speedup vs baseline: 1.1754x; 1.0650x over previous
//
#include <hip/hip_runtime.h>

#define Bn   2
#define Cn   64
#define Dd   8
#define Hd   128
#define Wd   128
#define HW   16384
#define DHW  131072     // 2^17
#define NPOS 262144     // 2^18
#define NELEM 16777216

typedef __attribute__((ext_vector_type(8))) short short8;
typedef __attribute__((ext_vector_type(4))) float floatx4;

__device__ __forceinline__ short f2bf(float f) {
    union { float f; unsigned u; } v; v.f = f;
    unsigned r = (v.u + 0x7FFFu + ((v.u >> 16) & 1u)) >> 16;   // RNE
    return (short)r;
}
__device__ __forceinline__ float bf2f(short s) {
    union { unsigned u; float f; } v; v.u = ((unsigned)(unsigned short)s) << 16;
    return v.f;
}
// Cheap truncation split: hi = upper16(f), lo = trunc16(f - hi). ~4 VALU ops.
// Pair error ~2^-17 relative — fp32-class for K=64 GEMMs.
__device__ __forceinline__ void split2(float f, short& hi, short& lo) {
    union { float f; unsigned u; } a; a.f = f;
    unsigned hu = a.u & 0xFFFF0000u;
    hi = (short)(hu >> 16);
    union { unsigned u; float f; } hb; hb.u = hu;
    union { float f; unsigned u; } lb; lb.f = f - hb.f;
    lo = (short)(lb.u >> 16);
}

// ---------------------------------------------------------------------------
// k_prep: split-bf16 weights. Wh{h,l}[80][64]: rows 0..63 = head_w,
// rows 64..66 = V^T @ head_w (folds Vp), rows 67..79 = 0. Wt{h,l}[64][64].
// ---------------------------------------------------------------------------
__global__ __launch_bounds__(256) void k_prep(const float* __restrict__ head_w,
                                              const float* __restrict__ tail_w,
                                              const float* __restrict__ V_w,
                                              short* __restrict__ Whh, short* __restrict__ Whl,
                                              short* __restrict__ Wth, short* __restrict__ Wtl)
{
    int t = threadIdx.x;
#pragma unroll
    for (int rep = 0; rep < 16; ++rep) {
        int idx = rep * 256 + t;            // 4096
        short hh, hl;
        split2(head_w[idx], hh, hl);
        Whh[idx] = hh; Whl[idx] = hl;
        split2(tail_w[idx], hh, hl);
        Wth[idx] = hh; Wtl[idx] = hl;
    }
    if (t < 192) {                          // VW[r][i] = sum_c V[c][r]*W[c][i]
        int r = t >> 6, i = t & 63;
        float s = 0.f;
        for (int cc = 0; cc < 64; ++cc) s += V_w[cc * 3 + r] * head_w[cc * 64 + i];
        short hh, hl;
        split2(s, hh, hl);
        Whh[(64 + r) * 64 + i] = hh;
        Whl[(64 + r) * 64 + i] = hl;
    }
#pragma unroll
    for (int rep = 0; rep < 4; ++rep) {     // zero rows 67..79 (832 entries)
        int idx = rep * 256 + t;
        if (idx < 832) { Whh[67 * 64 + idx] = 0; Whl[67 * 64 + idx] = 0; }
    }
}

// ---------------------------------------------------------------------------
// k_headm: [h | Vp] = Wh[80x64] @ x via split-bf16 MFMA (fp32-equivalent).
// 3-product split: ah*bh + ah*bl + al*bh (al*bl term ~2^-16 rel, dropped).
// Block = 128 positions. Fragment order in LDS; epilogue transposes C through
// LDS (row stride 132 floats, 16B-aligned, bank-optimal b128) so each global
// store instruction covers 2 rows x 512B contiguous.
// ---------------------------------------------------------------------------
__global__ __launch_bounds__(256) void k_headm(const float* __restrict__ x,
                                               const short* __restrict__ Whh,
                                               const short* __restrict__ Whl,
                                               float* __restrict__ h,
                                               float* __restrict__ Vp)
{
    __shared__ __align__(16) char smem[52 * 1024];
    short* Xh = (short*)smem;                    // 16 KB
    short* Xl = (short*)(smem + 16 * 1024);      // 16 KB
    short* Bh = (short*)(smem + 32 * 1024);      // 10 KB
    short* Bl = (short*)(smem + 42 * 1024);      // 10 KB
    float* Cb = (float*)smem;                    // epilogue: 80*132*4 = 42240 B

    int t  = threadIdx.x;
    int p0 = blockIdx.x * 128;
    int b  = p0 >> 17;
    int s0 = p0 & (DHW - 1);
    const float* xb = x + ((size_t)b * Cn) * DHW + s0;

    int pp = t & 127;
    int ho = t >> 7;
#pragma unroll
    for (int pass = 0; pass < 4; ++pass) {
        int in0 = pass * 16 + ho * 8;
        short8 vh, vl;
#pragma unroll
        for (int j = 0; j < 8; ++j) {
            short hh, hl;
            split2(xb[(size_t)(in0 + j) * DHW + pp], hh, hl);
            vh[j] = hh; vl[j] = hl;
        }
        int blk  = ((in0 >> 5) << 3) | (pp >> 4);
        int slot = (((in0 >> 3) & 3) << 4) | (pp & 15);
        *(short8*)&Xh[(blk * 64 + slot) * 8] = vh;
        *(short8*)&Xl[(blk * 64 + slot) * 8] = vl;
    }
#pragma unroll
    for (int pass = 0; pass < 3; ++pass) {   // 640 16B-units of Wh
        int unit = pass * 256 + t;
        if (unit < 640) {
            int o   = unit - (unit / 80) * 80;
            int oc  = unit / 80;
            int in0 = oc * 8;
            int blk  = ((o >> 4) << 1) | (in0 >> 5);
            int slot = (((in0 >> 3) & 3) << 4) | (o & 15);
            *(short8*)&Bh[(blk * 64 + slot) * 8] = *(const short8*)&Whh[o * 64 + in0];
            *(short8*)&Bl[(blk * 64 + slot) * 8] = *(const short8*)&Whl[o * 64 + in0];
        }
    }
    __syncthreads();

    int lane = t & 63;
    int w    = t >> 6;
    floatx4 acc[2][5];
#pragma unroll
    for (int mt = 0; mt < 2; ++mt)
#pragma unroll
        for (int nt = 0; nt < 5; ++nt) acc[mt][nt] = (floatx4)0.f;

    const short8* XhV = (const short8*)Xh;
    const short8* XlV = (const short8*)Xl;
    const short8* BhV = (const short8*)Bh;
    const short8* BlV = (const short8*)Bl;
#pragma unroll
    for (int ks = 0; ks < 2; ++ks) {
        short8 ah0 = XhV[(ks * 8 + w * 2 + 0) * 64 + lane];
        short8 ah1 = XhV[(ks * 8 + w * 2 + 1) * 64 + lane];
        short8 al0 = XlV[(ks * 8 + w * 2 + 0) * 64 + lane];
        short8 al1 = XlV[(ks * 8 + w * 2 + 1) * 64 + lane];
#pragma unroll
        for (int nt = 0; nt < 5; ++nt) {
            short8 bh = BhV[(nt * 2 + ks) * 64 + lane];
            short8 bl = BlV[(nt * 2 + ks) * 64 + lane];
            acc[0][nt] = __builtin_amdgcn_mfma_f32_16x16x32_bf16(al0, bh, acc[0][nt], 0, 0, 0);
            acc[0][nt] = __builtin_amdgcn_mfma_f32_16x16x32_bf16(ah0, bl, acc[0][nt], 0, 0, 0);
            acc[0][nt] = __builtin_amdgcn_mfma_f32_16x16x32_bf16(ah0, bh, acc[0][nt], 0, 0, 0);
            acc[1][nt] = __builtin_amdgcn_mfma_f32_16x16x32_bf16(al1, bh, acc[1][nt], 0, 0, 0);
            acc[1][nt] = __builtin_amdgcn_mfma_f32_16x16x32_bf16(ah1, bl, acc[1][nt], 0, 0, 0);
            acc[1][nt] = __builtin_amdgcn_mfma_f32_16x16x32_bf16(ah1, bh, acc[1][nt], 0, 0, 0);
        }
    }

    __syncthreads();                        // frag reads done; reuse LDS as Cb
    int outc = lane & 15;
    int quad = lane >> 4;
#pragma unroll
    for (int mt = 0; mt < 2; ++mt)
#pragma unroll
        for (int nt = 0; nt < 5; ++nt) {
            int o   = nt * 16 + outc;
            int pos = w * 32 + mt * 16 + quad * 4;
            *(floatx4*)&Cb[o * 132 + pos] = acc[mt][nt];
        }
    __syncthreads();

    int xr = (t & 31) * 4;                  // 0..124
    int ob = t >> 5;                        // 0..7
#pragma unroll
    for (int pass = 0; pass < 9; ++pass) {
        int o = pass * 8 + ob;
        floatx4 vv = *(const floatx4*)&Cb[o * 132 + xr];
        if (o < 64) {
            *(floatx4*)&h[((size_t)(b * Cn + o)) * DHW + s0 + xr] = vv;
        } else if (o < 67) {
            *(floatx4*)&Vp[((size_t)(b * 3 + (o - 64))) * DHW + s0 + xr] = vv;
        }
    }
}

// ---------------------------------------------------------------------------
// k_uv: fp32 depthwise 3x3x3 (replicate pad) -> l2norm over r -> dot Vp.
// Slice-major register schedule; 2-row tile / 16 KB LDS (best wall config).
// Output UV is written as bf16 (RNE): post-normalization precision, ~2^-9
// relative — out error ~2e-3 abs. Halves UV traffic and tailm's staging.
// ---------------------------------------------------------------------------
__global__ __launch_bounds__(256) void k_uv(const float* __restrict__ h,
                                            const float* __restrict__ Vp,
                                            const float* __restrict__ U_w,
                                            unsigned short* __restrict__ UVq)
{
    __shared__ float tile[Dd][4][Wd];   // 16 KB

    int blk = blockIdx.x;
    int yt  = blk & 63;
    int bc  = blk >> 6;                 // b*64 + c
    int b   = bc >> 6;
    int y0  = yt * 2;
    int t   = threadIdx.x;

    const float* hb = h + (size_t)bc * DHW;
#pragma unroll
    for (int rep = 0; rep < 4; ++rep) {   // 1024 float4 units
        int idx = rep * 256 + t;
        int d   = idx >> 7;
        int rem = idx & 127;
        int yr  = rem >> 5;
        int x4  = (rem & 31) * 4;
        int zy  = y0 - 1 + yr;
        zy = zy < 0 ? 0 : (zy > Hd - 1 ? Hd - 1 : zy);
        *(floatx4*)&tile[d][yr][x4] = *(const floatx4*)(hb + d * HW + zy * Wd + x4);
    }
    __syncthreads();

    int xx = t & 127;
    int yr = t >> 7;
    int y  = y0 + yr;
    int xm = xx - 1; if (xm < 0) xm = 0;
    int xp = xx + 1; if (xp > Wd - 1) xp = Wd - 1;

    float a0[8], a1[8], a2[8];
#pragma unroll
    for (int d = 0; d < 8; ++d) { a0[d] = 0.f; a1[d] = 0.f; a2[d] = 0.f; }

#define CONTRIB(dd, dk)                                                   \
    {                                                                     \
        _Pragma("unroll")                                                 \
        for (int kh = 0; kh < 3; ++kh) {                                  \
            _Pragma("unroll")                                             \
            for (int kw = 0; kw < 3; ++kw) {                              \
                const int kk = (((dk) * 3 + kh) * 3 + kw) * 3;            \
                a0[dd] += v[kh][kw] * U_w[kk + 0];                        \
                a1[dd] += v[kh][kw] * U_w[kk + 1];                        \
                a2[dd] += v[kh][kw] * U_w[kk + 2];                        \
            }                                                             \
        }                                                                 \
    }

#pragma unroll
    for (int sl = 0; sl < 8; ++sl) {
        float v[3][3];
#pragma unroll
        for (int kh = 0; kh < 3; ++kh) {
            const float* row = &tile[sl][yr + kh][0];
            v[kh][0] = row[xm]; v[kh][1] = row[xx]; v[kh][2] = row[xp];
        }
        CONTRIB(sl, 1);                         // dk=1 -> d = sl
        if (sl == 0) CONTRIB(0, 0);             // replicate clamp low
        if (sl < 7)  CONTRIB(sl + 1, 0);        // dk=0 -> d = sl+1
        if (sl > 0)  CONTRIB(sl - 1, 2);        // dk=2 -> d = sl-1
        if (sl == 7) CONTRIB(7, 2);             // replicate clamp high
    }
#undef CONTRIB

    const float* vpb    = Vp + (size_t)b * 3 * DHW + y * Wd + xx;
    unsigned short* uvb = UVq + (size_t)bc * DHW + y * Wd + xx;
#pragma unroll
    for (int d = 0; d < 8; ++d) {
        float nrm = sqrtf(a0[d] * a0[d] + a1[d] * a1[d] + a2[d] * a2[d]);
        float inv = 1.f / (1e-6f + nrm);
        float uv = (a0[d] * vpb[(size_t)d * HW]
                  + a1[d] * vpb[(size_t)DHW + d * HW]
                  + a2[d] * vpb[(size_t)2 * DHW + d * HW]) * inv;
        uvb[(size_t)d * HW] = (unsigned short)f2bf(uv);
    }
}

// ---------------------------------------------------------------------------
// k_tailm: out = Wt[64x64] @ UV(bf16) via MFMA; W split (a*bh + a*bl).
// X staging: plain bf16 loads, no split2, single 16 KB X buffer.
// LDS 33 KB -> 4 blocks/CU (was 3). 32 MFMA/thread (was 48).
// ---------------------------------------------------------------------------
__global__ __launch_bounds__(256) void k_tailm(const unsigned short* __restrict__ UVq,
                                               const short* __restrict__ Wth,
                                               const short* __restrict__ Wtl,
                                               float* __restrict__ out)
{
    __shared__ __align__(16) char smem[34 * 1024];
    short* Xh = (short*)smem;                    // 16 KB
    short* Bh = (short*)(smem + 16 * 1024);      // 8 KB
    short* Bl = (short*)(smem + 24 * 1024);      // 8 KB
    float* Cb = (float*)smem;                    // 64*132*4 = 33792 B

    int t  = threadIdx.x;
    int p0 = blockIdx.x * 128;
    int b  = p0 >> 17;
    int s0 = p0 & (DHW - 1);
    const unsigned short* uq = UVq + ((size_t)b * Cn) * DHW + s0;

    int pp = t & 127;
    int ho = t >> 7;
#pragma unroll
    for (int pass = 0; pass < 4; ++pass) {
        int in0 = pass * 16 + ho * 8;
        short8 vh;
#pragma unroll
        for (int j = 0; j < 8; ++j)
            vh[j] = (short)uq[(size_t)(in0 + j) * DHW + pp];
        int blk  = ((in0 >> 5) << 3) | (pp >> 4);
        int slot = (((in0 >> 3) & 3) << 4) | (pp & 15);
        *(short8*)&Xh[(blk * 64 + slot) * 8] = vh;
    }
#pragma unroll
    for (int pass = 0; pass < 2; ++pass) {   // 512 16B-units of Wt
        int unit = pass * 256 + t;
        int o    = unit & 63;
        int oc   = unit >> 6;
        int in0  = oc * 8;
        int blk  = ((o >> 4) << 1) | (in0 >> 5);
        int slot = (((in0 >> 3) & 3) << 4) | (o & 15);
        *(short8*)&Bh[(blk * 64 + slot) * 8] = *(const short8*)&Wth[o * 64 + in0];
        *(short8*)&Bl[(blk * 64 + slot) * 8] = *(const short8*)&Wtl[o * 64 + in0];
    }
    __syncthreads();

    int lane = t & 63;
    int w    = t >> 6;
    floatx4 acc[2][4];
#pragma unroll
    for (int mt = 0; mt < 2; ++mt)
#pragma unroll
        for (int nt = 0; nt < 4; ++nt) acc[mt][nt] = (floatx4)0.f;

    const short8* XhV = (const short8*)Xh;
    const short8* BhV = (const short8*)Bh;
    const short8* BlV = (const short8*)Bl;
#pragma unroll
    for (int ks = 0; ks < 2; ++ks) {
        short8 ah0 = XhV[(ks * 8 + w * 2 + 0) * 64 + lane];
        short8 ah1 = XhV[(ks * 8 + w * 2 + 1) * 64 + lane];
#pragma unroll
        for (int nt = 0; nt < 4; ++nt) {
            short8 bh = BhV[(nt * 2 + ks) * 64 + lane];
            short8 bl = BlV[(nt * 2 + ks) * 64 + lane];
            acc[0][nt] = __builtin_amdgcn_mfma_f32_16x16x32_bf16(ah0, bl, acc[0][nt], 0, 0, 0);
            acc[0][nt] = __builtin_amdgcn_mfma_f32_16x16x32_bf16(ah0, bh, acc[0][nt], 0, 0, 0);
            acc[1][nt] = __builtin_amdgcn_mfma_f32_16x16x32_bf16(ah1, bl, acc[1][nt], 0, 0, 0);
            acc[1][nt] = __builtin_amdgcn_mfma_f32_16x16x32_bf16(ah1, bh, acc[1][nt], 0, 0, 0);
        }
    }

    __syncthreads();
    int outc = lane & 15;
    int quad = lane >> 4;
#pragma unroll
    for (int mt = 0; mt < 2; ++mt)
#pragma unroll
        for (int nt = 0; nt < 4; ++nt) {
            int o   = nt * 16 + outc;
            int pos = w * 32 + mt * 16 + quad * 4;
            *(floatx4*)&Cb[o * 132 + pos] = acc[mt][nt];
        }
    __syncthreads();

    int xr = (t & 31) * 4;
    int ob = t >> 5;
#pragma unroll
    for (int pass = 0; pass < 8; ++pass) {
        int o = pass * 8 + ob;
        floatx4 vv = *(const floatx4*)&Cb[o * 132 + xr];
        *(floatx4*)&out[((size_t)(b * Cn + o)) * DHW + s0 + xr] = vv;
    }
}

extern "C" void kernel_launch(void* const* d_in, const int* in_sizes, int n_in,
                              void* d_out, int out_size, void* d_ws, size_t ws_size,
                              hipStream_t stream)
{
    const float* x      = (const float*)d_in[0];
    const float* head_w = (const float*)d_in[1];
    const float* tail_w = (const float*)d_in[2];
    const float* U_w    = (const float*)d_in[3];
    const float* V_w    = (const float*)d_in[4];
    float* out = (float*)d_out;

    // ws: h fp32 (64MB) | Vp fp32 (3MB) | UVq bf16 (32MB) | split weights
    float* h   = (float*)d_ws;
    float* Vp  = h + (size_t)NELEM;
    unsigned short* UVq = (unsigned short*)(Vp + (size_t)Bn * 3 * DHW);
    short* Whh = (short*)(UVq + (size_t)NELEM);
    short* Whl = Whh + 80 * 64;
    short* Wth = Whl + 80 * 64;
    short* Wtl = Wth + 64 * 64;

    k_prep<<<1, 256, 0, stream>>>(head_w, tail_w, V_w, Whh, Whl, Wth, Wtl);
    k_headm<<<NPOS / 128, 256, 0, stream>>>(x, Whh, Whl, h, Vp);
    k_uv<<<Bn * Cn * (Hd / 2), 256, 0, stream>>>(h, Vp, U_w, UVq);
    k_tailm<<<NPOS / 128, 256, 0, stream>>>(UVq, Wth, Wtl, out);
}